// Round 2
// baseline (141.704 us; speedup 1.0000x reference)
//
#include <hip/hip_runtime.h>

#define NCLUSTER 512
#define NC 3
#define HW 65536

// Certified-exact fp32 fast path:
//   argmin_k d_k  ==  argmin_k t_k,  t_k = 0.5*||C_k||^2 - x.C_k
// fp32 rounding of t_k is bounded by ~4*ulp(70) ~= 1.6e-5 (intermediate
// magnitudes <= ~70 for these gaussian inputs). If the top-2 gap exceeds
// EPS = 1e-4 (>3x the two-score bound), the fp32 argmin is provably the true
// argmin. Otherwise fall back to the fp64 direct form (validated exact in R1,
// absmax 0.0).
#define EPS 1e-4f

__global__ void kmeans_prep(const float* __restrict__ C, float4* __restrict__ Cws) {
    int k = blockIdx.x * blockDim.x + threadIdx.x;
    if (k < NCLUSTER) {
        double c0 = C[k * NC + 0];
        double c1 = C[k * NC + 1];
        double c2 = C[k * NC + 2];
        float h = (float)(0.5 * (c0 * c0 + c1 * c1 + c2 * c2));
        Cws[k] = make_float4((float)c0, (float)c1, (float)c2, h);
    }
}

__global__ __launch_bounds__(256) void kmeans_assign(
    const float* __restrict__ x,     // [4,3,256,256]
    const float* __restrict__ C,     // [512,3] raw (fp64 fallback path)
    const float4* __restrict__ Cws,  // [512] {c0,c1,c2,0.5*||c||^2}
    int* __restrict__ out,           // [4,65536]
    int total)
{
    int tid = blockIdx.x * blockDim.x + threadIdx.x;
    if (tid >= total) return;

    int b = tid >> 16;
    int p = tid & (HW - 1);
    const float* xb = x + (size_t)b * NC * HW + p;
    float x0 = xb[0];
    float x1 = xb[HW];
    float x2 = xb[2 * HW];

    float best1 = 1e30f;   // min score
    float best2 = 1e30f;   // exact second-min score
    int idx = 0;

    // k is wave-uniform -> Cws[k] compiles to s_load_dwordx4 (scalar cache);
    // the loop body is pure VALU with SGPR operands.
#pragma unroll 8
    for (int k = 0; k < NCLUSTER; ++k) {
        float4 c = Cws[k];
        float t = c.w;
        t = __builtin_fmaf(-x0, c.x, t);
        t = __builtin_fmaf(-x1, c.y, t);
        t = __builtin_fmaf(-x2, c.z, t);
        bool lt = t < best1;                        // strict: keep first index
        best2 = lt ? best1 : fminf(best2, t);
        best1 = fminf(best1, t);
        idx = lt ? k : idx;
    }

    if (best2 - best1 < EPS) {
        // Rare near-tie: exact fp64 direct-form rescan (matches reference).
        double X0 = x0, X1 = x1, X2 = x2;
        double bd = 1e300;
        int bi = 0;
        for (int k = 0; k < NCLUSTER; ++k) {
            double d0 = X0 - (double)C[k * NC + 0];
            double d1 = X1 - (double)C[k * NC + 1];
            double d2 = X2 - (double)C[k * NC + 2];
            double d = d0 * d0 + d1 * d1 + d2 * d2;
            if (d < bd) { bd = d; bi = k; }
        }
        idx = bi;
    }

    out[tid] = idx;
}

extern "C" void kernel_launch(void* const* d_in, const int* in_sizes, int n_in,
                              void* d_out, int out_size, void* d_ws, size_t ws_size,
                              hipStream_t stream) {
    const float* x = (const float*)d_in[0];
    const float* C = (const float*)d_in[1];
    int* out = (int*)d_out;
    float4* Cws = (float4*)d_ws;  // 512 * 16 B = 8 KiB scratch

    kmeans_prep<<<2, 256, 0, stream>>>(C, Cws);

    int total = out_size;  // 262144
    int block = 256;
    int grid = (total + block - 1) / block;
    kmeans_assign<<<grid, block, 0, stream>>>(x, C, Cws, out, total);
}